// Round 14
// baseline (97.282 us; speedup 1.0000x reference)
//
#include <hip/hip_runtime.h>
#include <hip/hip_bf16.h>
#include <math.h>

#define BATCH    4
#define NPTS     8192
#define NSIDE    (BATCH * NPTS)     // 32768 points per side
#define NMINS    (2 * NSIDE)        // 65536 per-query mins
#define THREADS  256
#define RTHREADS 1024
#define INF_BITS 0x7F800000u

// ws layout: [0, 2MB) FB records; [2MB, 2.25MB) uint mins; [4MB, ...) probe dump
#define WS_MIN_OFF  (2ull * NSIDE * 32)
#define WS_DUMP_OFF (4ull * 1024 * 1024)

typedef __attribute__((ext_vector_type(8)))  short s16x8;   // 8 bf16 = 4 VGPR (MFMA A/B frag)
typedef __attribute__((ext_vector_type(16))) float f32x16;  // MFMA C/D frag

__device__ __forceinline__ short bfbits(float x) {
    union { __hip_bfloat16 b; unsigned short u; } cv;
    cv.b = __float2bfloat16(x);
    return (short)cv.u;
}
__device__ __forceinline__ float bfval(float x) {
    return __bfloat162float(__float2bfloat16(x));
}

// Slot plan (K=16), P = -2 q.c + rq + rc  (validated R7-R13, absmax 0).
__global__ __launch_bounds__(THREADS) void chamfer_pre(const float* __restrict__ preds,
                                                       const float* __restrict__ gts,
                                                       s16x8* __restrict__ FBv,
                                                       unsigned int* __restrict__ wsmin) {
    int i = blockIdx.x * THREADS + threadIdx.x;    // 0..65535
    int side = i >> 15;                            // 0: preds, 1: gts
    int n = i & (NSIDE - 1);
    const float* src = side ? gts : preds;
    float x = src[3*n], y = src[3*n+1], z = src[3*n+2];
    float rq = fmaf(x, x, fmaf(y, y, z*z));
    float xh = bfval(x), yh = bfval(y), zh = bfval(z), rh = bfval(rq);
    const short one = (short)0x3F80;
    s16x8 lo, hi;
    lo[0] = bfbits(xh);     lo[1] = bfbits(x - xh);
    lo[2] = lo[0];          lo[3] = lo[1];
    lo[4] = bfbits(yh);     lo[5] = bfbits(y - yh);
    lo[6] = lo[4];          lo[7] = lo[5];
    hi[0] = bfbits(zh);     hi[1] = bfbits(z - zh);
    hi[2] = hi[0];          hi[3] = hi[1];
    hi[4] = one;            hi[5] = one;
    hi[6] = bfbits(rh);     hi[7] = bfbits(rq - rh);
    FBv[2*(size_t)i]     = lo;
    FBv[2*(size_t)i + 1] = hi;
    wsmin[i] = INF_BITS;
}

__device__ __forceinline__ s16x8 make_afrag(const float* __restrict__ Q, int row, int h) {
    const short one = (short)0x3F80;
    float x = Q[3*row], y = Q[3*row+1], z = Q[3*row+2];
    float rq = fmaf(x, x, fmaf(y, y, z*z));
    float xh = bfval(x), yh = bfval(y), zh = bfval(z), rh = bfval(rq);
    s16x8 r;
    if (h == 0) {
        short mh = bfbits(-2.f*xh), ml = bfbits(-2.f*(x - xh));
        short nh = bfbits(-2.f*yh), nl = bfbits(-2.f*(y - yh));
        r[0]=mh; r[1]=mh; r[2]=ml; r[3]=ml;
        r[4]=nh; r[5]=nh; r[6]=nl; r[7]=nl;
    } else {
        short mh = bfbits(-2.f*zh), ml = bfbits(-2.f*(z - zh));
        r[0]=mh; r[1]=mh; r[2]=ml; r[3]=ml;
        r[4]=bfbits(rh); r[5]=bfbits(rq - rh); r[6]=one; r[7]=one;
    }
    return r;
}

// ======== MAIN: R10 verbatim (best known: 37.1 total) ========
__global__ __launch_bounds__(THREADS, 4) void chamfer_mfma(const float* __restrict__ preds,
                                                           const float* __restrict__ gts,
                                                           const s16x8* __restrict__ FBv,
                                                           unsigned int* __restrict__ wsmin) {
    const int rb  = blockIdx.x;
    const int cq  = blockIdx.y;
    const int dbz = blockIdx.z;
    const int dir = dbz >> 2, b = dbz & 3;

    const int t = threadIdx.x, lane = t & 63, wid = t >> 6;
    const int li = lane & 31, h = lane >> 5;

    const float* __restrict__ Q = (dir ? gts : preds) + (size_t)b * NPTS * 3;
    const s16x8* __restrict__ FBb =
        FBv + 2ull * (((size_t)(dir ^ 1) * BATCH + b) * NPTS + (size_t)cq * 2048);

    const int row0 = rb * 256 + wid * 64 + li;
    const s16x8 a0 = make_afrag(Q, row0,      h);
    const s16x8 a1 = make_afrag(Q, row0 + 32, h);

    const s16x8* __restrict__ Bp = FBb + 2*li + h;

    f32x16 zero = {};
    float rmin0[16], rmin1[16];
    #pragma unroll
    for (int r = 0; r < 16; ++r) { rmin0[r] = INFINITY; rmin1[r] = INFINITY; }

    s16x8 c0 = Bp[0],   c1 = Bp[64];
    s16x8 n0 = Bp[128], n1 = Bp[192];

    #pragma unroll 1
    for (int jp = 0; jp < 32; jp += 2) {
        const int j2 = (jp + 2) & 31, j3 = (jp + 3) & 31;

        s16x8 f0 = Bp[(size_t)j2 * 128], f1 = Bp[(size_t)j2 * 128 + 64];
        {
            __builtin_amdgcn_s_setprio(1);
            f32x16 d0 = __builtin_amdgcn_mfma_f32_32x32x16_bf16(a0, c0, zero, 0, 0, 0);
            f32x16 d1 = __builtin_amdgcn_mfma_f32_32x32x16_bf16(a0, c1, zero, 0, 0, 0);
            __builtin_amdgcn_s_setprio(0);
            #pragma unroll
            for (int r = 0; r < 16; ++r) rmin0[r] = fminf(fminf(rmin0[r], d0[r]), d1[r]);
        }
        {
            __builtin_amdgcn_s_setprio(1);
            f32x16 d0 = __builtin_amdgcn_mfma_f32_32x32x16_bf16(a1, c0, zero, 0, 0, 0);
            f32x16 d1 = __builtin_amdgcn_mfma_f32_32x32x16_bf16(a1, c1, zero, 0, 0, 0);
            __builtin_amdgcn_s_setprio(0);
            #pragma unroll
            for (int r = 0; r < 16; ++r) rmin1[r] = fminf(fminf(rmin1[r], d0[r]), d1[r]);
        }

        s16x8 g0 = Bp[(size_t)j3 * 128], g1 = Bp[(size_t)j3 * 128 + 64];
        {
            __builtin_amdgcn_s_setprio(1);
            f32x16 d0 = __builtin_amdgcn_mfma_f32_32x32x16_bf16(a0, n0, zero, 0, 0, 0);
            f32x16 d1 = __builtin_amdgcn_mfma_f32_32x32x16_bf16(a0, n1, zero, 0, 0, 0);
            __builtin_amdgcn_s_setprio(0);
            #pragma unroll
            for (int r = 0; r < 16; ++r) rmin0[r] = fminf(fminf(rmin0[r], d0[r]), d1[r]);
        }
        {
            __builtin_amdgcn_s_setprio(1);
            f32x16 d0 = __builtin_amdgcn_mfma_f32_32x32x16_bf16(a1, n0, zero, 0, 0, 0);
            f32x16 d1 = __builtin_amdgcn_mfma_f32_32x32x16_bf16(a1, n1, zero, 0, 0, 0);
            __builtin_amdgcn_s_setprio(0);
            #pragma unroll
            for (int r = 0; r < 16; ++r) rmin1[r] = fminf(fminf(rmin1[r], d0[r]), d1[r]);
        }

        c0 = f0; c1 = f1; n0 = g0; n1 = g1;
    }

    unsigned int* __restrict__ wbase = wsmin + ((size_t)dir * BATCH + b) * NPTS;
    #pragma unroll
    for (int r = 0; r < 16; ++r) {
        float m0 = rmin0[r], m1 = rmin1[r];
        #pragma unroll
        for (int off = 1; off <= 16; off <<= 1) {
            m0 = fminf(m0, __shfl_xor(m0, off, 64));
            m1 = fminf(m1, __shfl_xor(m1, off, 64));
        }
        if (li == 0) {
            int rowin = (r & 3) + 8 * (r >> 2) + 4 * h;
            int rbase = rb * 256 + wid * 64 + rowin;
            atomicMin(&wbase[rbase     ], __float_as_uint(fmaxf(m0, 0.f)));
            atomicMin(&wbase[rbase + 32], __float_as_uint(fmaxf(m1, 0.f)));
        }
    }
}

// ======== PROBE P1: MFMA + loads, ZERO fold (2x length). Chained-acc keeps MFMAs live. ========
__global__ __launch_bounds__(THREADS, 4) void probe_mfma_loads(const float* __restrict__ preds,
                                                               const float* __restrict__ gts,
                                                               const s16x8* __restrict__ FBv,
                                                               float* __restrict__ dump) {
    const int rb = blockIdx.x, cq = blockIdx.y, dbz = blockIdx.z;
    const int dir = dbz >> 2, b = dbz & 3;
    const int t = threadIdx.x, lane = t & 63, wid = t >> 6;
    const int li = lane & 31, h = lane >> 5;

    const float* __restrict__ Q = (dir ? gts : preds) + (size_t)b * NPTS * 3;
    const s16x8* __restrict__ FBb =
        FBv + 2ull * (((size_t)(dir ^ 1) * BATCH + b) * NPTS + (size_t)cq * 2048);
    const int row0 = rb * 256 + wid * 64 + li;
    const s16x8 a0 = make_afrag(Q, row0, h);
    const s16x8 a1 = make_afrag(Q, row0 + 32, h);
    const s16x8* __restrict__ Bp = FBb + 2*li + h;

    f32x16 acc0 = {}, acc1 = {}, acc2 = {}, acc3 = {};
    s16x8 c0 = Bp[0], c1 = Bp[64], n0 = Bp[128], n1 = Bp[192];

    #pragma unroll 1
    for (int jp = 0; jp < 64; jp += 2) {          // 2x main's trip count
        const int j2 = (jp + 2) & 31, j3 = (jp + 3) & 31;
        s16x8 f0 = Bp[(size_t)j2 * 128], f1 = Bp[(size_t)j2 * 128 + 64];
        acc0 = __builtin_amdgcn_mfma_f32_32x32x16_bf16(a0, c0, acc0, 0, 0, 0);
        acc1 = __builtin_amdgcn_mfma_f32_32x32x16_bf16(a0, c1, acc1, 0, 0, 0);
        acc2 = __builtin_amdgcn_mfma_f32_32x32x16_bf16(a1, c0, acc2, 0, 0, 0);
        acc3 = __builtin_amdgcn_mfma_f32_32x32x16_bf16(a1, c1, acc3, 0, 0, 0);
        s16x8 g0 = Bp[(size_t)j3 * 128], g1 = Bp[(size_t)j3 * 128 + 64];
        acc0 = __builtin_amdgcn_mfma_f32_32x32x16_bf16(a0, n0, acc0, 0, 0, 0);
        acc1 = __builtin_amdgcn_mfma_f32_32x32x16_bf16(a0, n1, acc1, 0, 0, 0);
        acc2 = __builtin_amdgcn_mfma_f32_32x32x16_bf16(a1, n0, acc2, 0, 0, 0);
        acc3 = __builtin_amdgcn_mfma_f32_32x32x16_bf16(a1, n1, acc3, 0, 0, 0);
        c0 = f0; c1 = f1; n0 = g0; n1 = g1;
    }
    float s = acc0[0] + acc1[1] + acc2[2] + acc3[3];
    if (lane == 0) dump[((size_t)dbz * 4 + blockIdx.y) * 32 * 4 + blockIdx.x * 4 + wid] = s;
}

// ======== PROBE P3: MFMA + full fold, ZERO loads (2x length). B synthesized from regs. ========
__global__ __launch_bounds__(THREADS, 4) void probe_mfma_fold(const float* __restrict__ preds,
                                                              const float* __restrict__ gts,
                                                              float* __restrict__ dump) {
    const int rb = blockIdx.x, dbz = blockIdx.z;
    const int dir = dbz >> 2, b = dbz & 3;
    const int t = threadIdx.x, lane = t & 63, wid = t >> 6;
    const int li = lane & 31, h = lane >> 5;

    const float* __restrict__ Q = (dir ? gts : preds) + (size_t)b * NPTS * 3;
    const int row0 = rb * 256 + wid * 64 + li;
    const s16x8 a0 = make_afrag(Q, row0, h);
    const s16x8 a1 = make_afrag(Q, row0 + 32, h);
    const s16x8 s0 = a0, s1 = a1;                 // synthesized B operands (no memory)

    f32x16 zero = {};
    float rmin0[16], rmin1[16];
    #pragma unroll
    for (int r = 0; r < 16; ++r) { rmin0[r] = INFINITY; rmin1[r] = INFINITY; }

    #pragma unroll 1
    for (int jp = 0; jp < 64; jp += 2) {          // 2x main's trip count
        {
            __builtin_amdgcn_s_setprio(1);
            f32x16 d0 = __builtin_amdgcn_mfma_f32_32x32x16_bf16(a0, s0, zero, 0, 0, 0);
            f32x16 d1 = __builtin_amdgcn_mfma_f32_32x32x16_bf16(a0, s1, zero, 0, 0, 0);
            __builtin_amdgcn_s_setprio(0);
            #pragma unroll
            for (int r = 0; r < 16; ++r) rmin0[r] = fminf(fminf(rmin0[r], d0[r]), d1[r]);
        }
        {
            __builtin_amdgcn_s_setprio(1);
            f32x16 d0 = __builtin_amdgcn_mfma_f32_32x32x16_bf16(a1, s0, zero, 0, 0, 0);
            f32x16 d1 = __builtin_amdgcn_mfma_f32_32x32x16_bf16(a1, s1, zero, 0, 0, 0);
            __builtin_amdgcn_s_setprio(0);
            #pragma unroll
            for (int r = 0; r < 16; ++r) rmin1[r] = fminf(fminf(rmin1[r], d0[r]), d1[r]);
        }
        {
            __builtin_amdgcn_s_setprio(1);
            f32x16 d0 = __builtin_amdgcn_mfma_f32_32x32x16_bf16(a0, s1, zero, 0, 0, 0);
            f32x16 d1 = __builtin_amdgcn_mfma_f32_32x32x16_bf16(a0, s0, zero, 0, 0, 0);
            __builtin_amdgcn_s_setprio(0);
            #pragma unroll
            for (int r = 0; r < 16; ++r) rmin0[r] = fminf(fminf(rmin0[r], d0[r]), d1[r]);
        }
        {
            __builtin_amdgcn_s_setprio(1);
            f32x16 d0 = __builtin_amdgcn_mfma_f32_32x32x16_bf16(a1, s1, zero, 0, 0, 0);
            f32x16 d1 = __builtin_amdgcn_mfma_f32_32x32x16_bf16(a1, s0, zero, 0, 0, 0);
            __builtin_amdgcn_s_setprio(0);
            #pragma unroll
            for (int r = 0; r < 16; ++r) rmin1[r] = fminf(fminf(rmin1[r], d0[r]), d1[r]);
        }
    }
    float s = 0.f;
    #pragma unroll
    for (int r = 0; r < 16; ++r) s += rmin0[r] + rmin1[r];
    if (lane == 0) dump[65536 + ((size_t)dbz * 4 + blockIdx.y) * 32 * 4 + blockIdx.x * 4 + wid] = s;
}

__global__ __launch_bounds__(RTHREADS) void chamfer_reduce(const unsigned int* __restrict__ wsmin,
                                                           float* __restrict__ out) {
    const float4* __restrict__ v = (const float4*)wsmin;
    float s = 0.0f;
    int i = threadIdx.x;
    #pragma unroll
    for (int it = 0; it < NMINS / 4 / RTHREADS; ++it, i += RTHREADS) {
        float4 a = v[i];
        s += (a.x + a.y) + (a.z + a.w);
    }
    for (int off = 32; off; off >>= 1) s += __shfl_down(s, off, 64);
    __shared__ float sm[RTHREADS / 64];
    if ((threadIdx.x & 63) == 0) sm[threadIdx.x >> 6] = s;
    __syncthreads();
    if (threadIdx.x == 0) {
        float tt = 0.0f;
        #pragma unroll
        for (int w = 0; w < RTHREADS / 64; ++w) tt += sm[w];
        out[0] = tt / (float)NPTS;
    }
}

extern "C" void kernel_launch(void* const* d_in, const int* in_sizes, int n_in,
                              void* d_out, int out_size, void* d_ws, size_t ws_size,
                              hipStream_t stream) {
    const float* preds = (const float*)d_in[0];
    const float* gts   = (const float*)d_in[1];
    float* out = (float*)d_out;
    s16x8* FBv = (s16x8*)d_ws;
    unsigned int* wsmin = (unsigned int*)((char*)d_ws + WS_MIN_OFF);
    float* dump = (float*)((char*)d_ws + WS_DUMP_OFF);

    chamfer_pre<<<NMINS / THREADS, THREADS, 0, stream>>>(preds, gts, FBv, wsmin);

    dim3 grid(32, 4, 2 * BATCH);
    chamfer_mfma<<<grid, THREADS, 0, stream>>>(preds, gts, FBv, wsmin);

    chamfer_reduce<<<1, RTHREADS, 0, stream>>>(wsmin, out);

    // diagnostic probes (after the real pipeline; outputs to unused ws region)
    probe_mfma_loads<<<grid, THREADS, 0, stream>>>(preds, gts, FBv, dump);
    probe_mfma_fold<<<grid, THREADS, 0, stream>>>(preds, gts, dump);
}

// Round 16
// 38.314 us; speedup vs baseline: 2.5391x; 2.5391x over previous
//
#include <hip/hip_runtime.h>
#include <hip/hip_bf16.h>
#include <math.h>

#define BATCH    4
#define NPTS     8192
#define NSIDE    (BATCH * NPTS)     // 32768 points per side
#define NMINS    (2 * NSIDE)        // 65536 per-query mins
#define THREADS  256
#define RTHREADS 1024
#define INF_BITS 0x7F800000u

// ws layout: [0, 2MB) FB records (2 sides x 32768 x 16 bf16 = 32B); [2MB, 2.25MB) uint mins
#define WS_MIN_OFF (2ull * NSIDE * 32)

typedef __attribute__((ext_vector_type(8)))  short s16x8;   // 8 bf16 = 4 VGPR (MFMA A/B frag)
typedef __attribute__((ext_vector_type(16))) float f32x16;  // MFMA C/D frag

__device__ __forceinline__ short bfbits(float x) {
    union { __hip_bfloat16 b; unsigned short u; } cv;
    cv.b = __float2bfloat16(x);
    return (short)cv.u;
}
__device__ __forceinline__ float bfval(float x) {
    return __bfloat162float(__float2bfloat16(x));
}

// Slot plan (K=16), P = -2 q.c + rq + rc  (validated R7-R14, absmax 0):
//  k0..3: x: FA=(mxh,mxh,mxl,mxl) FB=(xh,xl,xh,xl); k4..7: y; k8..11: z
//  k12,13: FA=(rqh,rql) FB=(1,1);  k14,15: FA=(1,1) FB=(rch,rcl)

__global__ __launch_bounds__(THREADS) void chamfer_pre(const float* __restrict__ preds,
                                                       const float* __restrict__ gts,
                                                       s16x8* __restrict__ FBv,
                                                       unsigned int* __restrict__ wsmin) {
    int i = blockIdx.x * THREADS + threadIdx.x;    // 0..65535
    int side = i >> 15;                            // 0: preds, 1: gts
    int n = i & (NSIDE - 1);
    const float* src = side ? gts : preds;
    float x = src[3*n], y = src[3*n+1], z = src[3*n+2];
    float rq = fmaf(x, x, fmaf(y, y, z*z));
    float xh = bfval(x), yh = bfval(y), zh = bfval(z), rh = bfval(rq);
    const short one = (short)0x3F80;
    s16x8 lo, hi;
    lo[0] = bfbits(xh);     lo[1] = bfbits(x - xh);
    lo[2] = lo[0];          lo[3] = lo[1];
    lo[4] = bfbits(yh);     lo[5] = bfbits(y - yh);
    lo[6] = lo[4];          lo[7] = lo[5];
    hi[0] = bfbits(zh);     hi[1] = bfbits(z - zh);
    hi[2] = hi[0];          hi[3] = hi[1];
    hi[4] = one;            hi[5] = one;
    hi[6] = bfbits(rh);     hi[7] = bfbits(rq - rh);
    FBv[2*(size_t)i]     = lo;
    FBv[2*(size_t)i + 1] = hi;
    wsmin[i] = INF_BITS;
}

__device__ __forceinline__ s16x8 make_afrag(const float* __restrict__ Q, int row, int h) {
    const short one = (short)0x3F80;
    float x = Q[3*row], y = Q[3*row+1], z = Q[3*row+2];
    float rq = fmaf(x, x, fmaf(y, y, z*z));
    float xh = bfval(x), yh = bfval(y), zh = bfval(z), rh = bfval(rq);
    s16x8 r;
    if (h == 0) {
        short mh = bfbits(-2.f*xh), ml = bfbits(-2.f*(x - xh));
        short nh = bfbits(-2.f*yh), nl = bfbits(-2.f*(y - yh));
        r[0]=mh; r[1]=mh; r[2]=ml; r[3]=ml;
        r[4]=nh; r[5]=nh; r[6]=nl; r[7]=nl;
    } else {
        short mh = bfbits(-2.f*zh), ml = bfbits(-2.f*(z - zh));
        r[0]=mh; r[1]=mh; r[2]=ml; r[3]=ml;
        r[4]=bfbits(rh); r[5]=bfbits(rq - rh); r[6]=one; r[7]=one;
    }
    return r;
}

// Main: R10 structure; fold software-pipelined ONE MFMA behind its producer
// (each D gets ~2 MFMA issues (~64cy) of latency cover before its fold reads it).
// Pure intrinsics + fminf — no inline asm near MFMA results (R15 lesson).
__global__ __launch_bounds__(THREADS, 4) void chamfer_mfma(const float* __restrict__ preds,
                                                           const float* __restrict__ gts,
                                                           const s16x8* __restrict__ FBv,
                                                           unsigned int* __restrict__ wsmin) {
    const int rb  = blockIdx.x;        // 0..31 row-block (256 rows)
    const int cq  = blockIdx.y;        // 0..3 col quarter (2048 cols)
    const int dbz = blockIdx.z;        // dir*BATCH + b
    const int dir = dbz >> 2, b = dbz & 3;

    const int t = threadIdx.x, lane = t & 63, wid = t >> 6;
    const int li = lane & 31, h = lane >> 5;   // h: k-half

    const float* __restrict__ Q = (dir ? gts : preds) + (size_t)b * NPTS * 3;
    const s16x8* __restrict__ FBb =
        FBv + 2ull * (((size_t)(dir ^ 1) * BATCH + b) * NPTS + (size_t)cq * 2048);

    const int row0 = rb * 256 + wid * 64 + li;
    const s16x8 a0 = make_afrag(Q, row0,      h);
    const s16x8 a1 = make_afrag(Q, row0 + 32, h);

    const s16x8* __restrict__ Bp = FBb + 2*li + h;

    f32x16 zero = {};
    float rmin0[16], rmin1[16];
    #pragma unroll
    for (int r = 0; r < 16; ++r) { rmin0[r] = INFINITY; rmin1[r] = INFINITY; }

    // pipeline registers: pd01/pd11 = pending D-frags from previous tile-pair
    // (strip0/strip1 on tile c1). Prologue: +INF frags = fold identity.
    f32x16 pd01, pd11;
    #pragma unroll
    for (int r = 0; r < 16; ++r) { pd01[r] = INFINITY; pd11[r] = INFINITY; }

    s16x8 c0 = Bp[0], c1 = Bp[64];     // current tile pair

    #pragma unroll 1
    for (int jp = 0; jp < 32; ++jp) {
        const int nj = (jp + 1) & 31;                      // wrap: in-bounds, no branch
        s16x8 f0 = Bp[(size_t)nj * 128], f1 = Bp[(size_t)nj * 128 + 64];

        // interleave: issue MFMA(i); fold D(i-2)  -> ~64cy producer->consumer gap
        f32x16 d00 = __builtin_amdgcn_mfma_f32_32x32x16_bf16(a0, c0, zero, 0, 0, 0);
        #pragma unroll
        for (int r = 0; r < 16; ++r) rmin0[r] = fminf(rmin0[r], pd01[r]);

        f32x16 d10 = __builtin_amdgcn_mfma_f32_32x32x16_bf16(a1, c0, zero, 0, 0, 0);
        #pragma unroll
        for (int r = 0; r < 16; ++r) rmin1[r] = fminf(rmin1[r], pd11[r]);

        f32x16 d01 = __builtin_amdgcn_mfma_f32_32x32x16_bf16(a0, c1, zero, 0, 0, 0);
        #pragma unroll
        for (int r = 0; r < 16; ++r) rmin0[r] = fminf(rmin0[r], d00[r]);

        f32x16 d11 = __builtin_amdgcn_mfma_f32_32x32x16_bf16(a1, c1, zero, 0, 0, 0);
        #pragma unroll
        for (int r = 0; r < 16; ++r) rmin1[r] = fminf(rmin1[r], d10[r]);

        pd01 = d01; pd11 = d11;        // renames (SSA no-ops)
        c0 = f0; c1 = f1;
    }
    // drain pipeline
    #pragma unroll
    for (int r = 0; r < 16; ++r) rmin0[r] = fminf(rmin0[r], pd01[r]);
    #pragma unroll
    for (int r = 0; r < 16; ++r) rmin1[r] = fminf(rmin1[r], pd11[r]);

    // epilogue: min over 32 cols (xor<=16 keeps k-half), atomicMin per row
    unsigned int* __restrict__ wbase = wsmin + ((size_t)dir * BATCH + b) * NPTS;
    #pragma unroll
    for (int r = 0; r < 16; ++r) {
        float m0 = rmin0[r], m1 = rmin1[r];
        #pragma unroll
        for (int off = 1; off <= 16; off <<= 1) {
            m0 = fminf(m0, __shfl_xor(m0, off, 64));
            m1 = fminf(m1, __shfl_xor(m1, off, 64));
        }
        if (li == 0) {
            int rowin = (r & 3) + 8 * (r >> 2) + 4 * h;   // C/D row map (validated R7-R14)
            int rbase = rb * 256 + wid * 64 + rowin;
            atomicMin(&wbase[rbase     ], __float_as_uint(fmaxf(m0, 0.f)));
            atomicMin(&wbase[rbase + 32], __float_as_uint(fmaxf(m1, 0.f)));
        }
    }
}

__global__ __launch_bounds__(RTHREADS) void chamfer_reduce(const unsigned int* __restrict__ wsmin,
                                                           float* __restrict__ out) {
    const float4* __restrict__ v = (const float4*)wsmin;  // bits are valid floats (>=0)
    float s = 0.0f;
    int i = threadIdx.x;
    #pragma unroll
    for (int it = 0; it < NMINS / 4 / RTHREADS; ++it, i += RTHREADS) {
        float4 a = v[i];
        s += (a.x + a.y) + (a.z + a.w);
    }
    for (int off = 32; off; off >>= 1) s += __shfl_down(s, off, 64);
    __shared__ float sm[RTHREADS / 64];
    if ((threadIdx.x & 63) == 0) sm[threadIdx.x >> 6] = s;
    __syncthreads();
    if (threadIdx.x == 0) {
        float tt = 0.0f;
        #pragma unroll
        for (int w = 0; w < RTHREADS / 64; ++w) tt += sm[w];
        out[0] = tt / (float)NPTS;   // sum(mins1)/M + sum(mins2)/N, M=N=NPTS
    }
}

extern "C" void kernel_launch(void* const* d_in, const int* in_sizes, int n_in,
                              void* d_out, int out_size, void* d_ws, size_t ws_size,
                              hipStream_t stream) {
    const float* preds = (const float*)d_in[0];
    const float* gts   = (const float*)d_in[1];
    float* out = (float*)d_out;
    s16x8* FBv = (s16x8*)d_ws;
    unsigned int* wsmin = (unsigned int*)((char*)d_ws + WS_MIN_OFF);

    chamfer_pre<<<NMINS / THREADS, THREADS, 0, stream>>>(preds, gts, FBv, wsmin);

    dim3 grid(32, 4, 2 * BATCH);   // row-blocks x col-quarters x (dir*BATCH+b)
    chamfer_mfma<<<grid, THREADS, 0, stream>>>(preds, gts, FBv, wsmin);

    chamfer_reduce<<<1, RTHREADS, 0, stream>>>(wsmin, out);
}